// Round 1
// baseline (338.477 us; speedup 1.0000x reference)
//
#include <hip/hip_runtime.h>

// Problem constants: x [B=16, C=96, H=256, W=256] fp32, STRIDE=2, P_NORM=2.
// out [16, 96, 128, 128] fp32.
#define B  16
#define C  96
#define H  256
#define W  256
#define HO 128
#define WO 128

#define F4_PER_ROW   (W / 4)                 // 64 float4 per input row
#define F4_PER_BATCH (C * H * F4_PER_ROW)    // 1,572,864
#define OUT_F4       (B * C * HO * (WO / 4)) // 6,291,456
#define OUT_F4_PER_ROW (WO / 4)              // 32

// Pass 1: per (batch, phase) sum of squares. Grid: (128, B) x 256 threads.
// Each wave's 64 consecutive float4s lie in exactly one input row (rows are
// 64 float4s, all strides multiples of 64) -> h-parity is wave-uniform.
__global__ void aps_norms(const float4* __restrict__ in, float* __restrict__ acc) {
    const int b = blockIdx.y;
    const float4* base = in + (size_t)b * F4_PER_BATCH;
    float a00 = 0.f, a01 = 0.f, a10 = 0.f, a11 = 0.f; // [h&1][w&1]
    const int stride = gridDim.x * blockDim.x;
    for (int i = blockIdx.x * blockDim.x + threadIdx.x; i < F4_PER_BATCH; i += stride) {
        float4 v = base[i];
        float e = v.x * v.x + v.z * v.z;   // w even lanes of this float4
        float o = v.y * v.y + v.w * v.w;   // w odd lanes
        if ((i >> 6) & 1) { a10 += e; a11 += o; }  // wave-uniform branch
        else              { a00 += e; a01 += o; }
    }
    // wave reduce each of the 4 accumulators, one atomic per wave per phase
    float vals0 = a00, vals1 = a01, vals2 = a10, vals3 = a11;
    #pragma unroll
    for (int off = 32; off; off >>= 1) {
        vals0 += __shfl_down(vals0, off);
        vals1 += __shfl_down(vals1, off);
        vals2 += __shfl_down(vals2, off);
        vals3 += __shfl_down(vals3, off);
    }
    if ((threadIdx.x & 63) == 0) {
        atomicAdd(&acc[b * 4 + 0], vals0);
        atomicAdd(&acc[b * 4 + 1], vals1);
        atomicAdd(&acc[b * 4 + 2], vals2);
        atomicAdd(&acc[b * 4 + 3], vals3);
    }
}

// Pass 2: argmax over 4 phases per batch; strict > keeps first max
// (matches jnp.argmax first-occurrence semantics).
__global__ void aps_argmax(const float* __restrict__ acc, int* __restrict__ idx) {
    int t = threadIdx.x;
    if (t < B) {
        float n0 = acc[t * 4 + 0], n1 = acc[t * 4 + 1];
        float n2 = acc[t * 4 + 2], n3 = acc[t * 4 + 3];
        int best = 0; float bm = n0;
        if (n1 > bm) { bm = n1; best = 1; }
        if (n2 > bm) { bm = n2; best = 2; }
        if (n3 > bm) { bm = n3; best = 3; }
        idx[t] = best;
    }
}

// Pass 3: gather winning phase. One output float4 (4 consecutive w') per
// thread; needs input cols 8t+j .. 8t+6+j, covered by two contiguous float4
// loads at cols 8t and 8t+4 -> fully coalesced reads and writes.
__global__ void aps_gather(const float4* __restrict__ in,
                           const int* __restrict__ idxArr,
                           float4* __restrict__ out) {
    int o = blockIdx.x * blockDim.x + threadIdx.x;   // output float4 index
    int t  = o & 31;          // float4 index within output row
    int hp = (o >> 5) & 127;  // output row h'
    int bc = o >> 12;         // b*C + c
    int b  = bc / C;
    int phase = idxArr[b];    // wave-uniform (same b across a wave)
    int i = phase >> 1, j = phase & 1;
    const float4* row = in + ((size_t)bc * H + (2 * hp + i)) * F4_PER_ROW;
    float4 a  = row[2 * t];
    float4 c4 = row[2 * t + 1];
    float4 r;
    r.x = j ? a.y  : a.x;
    r.y = j ? a.w  : a.z;
    r.z = j ? c4.y : c4.x;
    r.w = j ? c4.w : c4.z;
    out[o] = r;
}

extern "C" void kernel_launch(void* const* d_in, const int* in_sizes, int n_in,
                              void* d_out, int out_size, void* d_ws, size_t ws_size,
                              hipStream_t stream) {
    const float4* in = (const float4*)d_in[0];
    float4* out = (float4*)d_out;
    float* acc = (float*)d_ws;                 // 64 floats: [B][4] phase norms^2
    int* idx = (int*)((char*)d_ws + 256);      // 16 ints: winning phase per batch

    // zero the accumulators (harness does not re-poison between replays)
    hipMemsetAsync(d_ws, 0, 256, stream);

    dim3 g1(128, B);
    aps_norms<<<g1, 256, 0, stream>>>(in, acc);
    aps_argmax<<<1, 64, 0, stream>>>(acc, idx);
    aps_gather<<<OUT_F4 / 256, 256, 0, stream>>>(in, (const int*)idx, out);
}

// Round 2
// 130.553 us; speedup vs baseline: 2.5926x; 2.5926x over previous
//
#include <hip/hip_runtime.h>

// Problem constants: x [B=16, C=96, H=256, W=256] fp32, STRIDE=2, P_NORM=2.
// out [16, 96, 128, 128] fp32.
#define B  16
#define C  96
#define H  256
#define W  256
#define HO 128
#define WO 128

#define F4_PER_ROW   (W / 4)                 // 64 float4 per input row
#define F4_PER_BATCH (C * H * F4_PER_ROW)    // 1,572,864
#define OUT_F4       (B * C * HO * (WO / 4)) // 6,291,456
#define GX   128                             // blocks per batch, pass 1
#define BLK  256

// d_ws layout: partial[(b*4 + p)*GX + gx]  -> 16*4*128 floats = 32 KB
//              idx[b]                      -> at byte offset 32768

// Pass 1: per (batch, phase) sum of squares, NO atomics.
// Grid (GX, B) x BLK. Each wave's 64 consecutive float4s lie in one input
// row (rows are 64 float4s; stride/64 = 512 is even) -> h-parity is
// wave-uniform AND identical across the 4 unrolled loads.
__global__ void aps_norms(const float4* __restrict__ in, float* __restrict__ partial) {
    const int b = blockIdx.y;
    const float4* base = in + (size_t)b * F4_PER_BATCH;
    float a00 = 0.f, a01 = 0.f, a10 = 0.f, a11 = 0.f; // [h&1][w&1]
    const int stride = GX * BLK;                       // 32768
    // 48 float4s per thread, exactly 12 iterations of x4 unroll.
    for (int i = blockIdx.x * BLK + threadIdx.x; i < F4_PER_BATCH; i += 4 * stride) {
        float4 v0 = base[i];
        float4 v1 = base[i + stride];
        float4 v2 = base[i + 2 * stride];
        float4 v3 = base[i + 3 * stride];
        float e = v0.x * v0.x + v0.z * v0.z + v1.x * v1.x + v1.z * v1.z
                + v2.x * v2.x + v2.z * v2.z + v3.x * v3.x + v3.z * v3.z;
        float o = v0.y * v0.y + v0.w * v0.w + v1.y * v1.y + v1.w * v1.w
                + v2.y * v2.y + v2.w * v2.w + v3.y * v3.y + v3.w * v3.w;
        if ((i >> 6) & 1) { a10 += e; a11 += o; }      // wave-uniform branch
        else              { a00 += e; a01 += o; }
    }
    // wave-level shfl reduction of the 4 accumulators
    #pragma unroll
    for (int off = 32; off; off >>= 1) {
        a00 += __shfl_down(a00, off);
        a01 += __shfl_down(a01, off);
        a10 += __shfl_down(a10, off);
        a11 += __shfl_down(a11, off);
    }
    __shared__ float sm[4][4];                          // [wave][phase]
    const int wave = threadIdx.x >> 6, lane = threadIdx.x & 63;
    if (lane == 0) {
        sm[wave][0] = a00; sm[wave][1] = a01; sm[wave][2] = a10; sm[wave][3] = a11;
    }
    __syncthreads();
    if (threadIdx.x < 4) {                              // one store per phase
        const int p = threadIdx.x;
        float s = sm[0][p] + sm[1][p] + sm[2][p] + sm[3][p];
        partial[(b * 4 + p) * GX + blockIdx.x] = s;
    }
}

// Pass 2: one block, 16 waves; wave b reduces batch b's 128 partials per
// phase and writes argmax. Strict > keeps first max (jnp.argmax semantics).
// Fixed reduction order -> deterministic across replays.
__global__ void aps_reduce_argmax(const float* __restrict__ partial, int* __restrict__ idx) {
    const int b = threadIdx.x >> 6, lane = threadIdx.x & 63;
    float s[4];
    #pragma unroll
    for (int p = 0; p < 4; ++p) {
        const float* pp = partial + (b * 4 + p) * GX;
        float v = pp[lane] + pp[lane + 64];
        #pragma unroll
        for (int off = 32; off; off >>= 1) v += __shfl_down(v, off);
        s[p] = v;
    }
    if (lane == 0) {
        int best = 0; float bm = s[0];
        if (s[1] > bm) { bm = s[1]; best = 1; }
        if (s[2] > bm) { bm = s[2]; best = 2; }
        if (s[3] > bm) { bm = s[3]; best = 3; }
        idx[b] = best;
    }
}

// Pass 3: gather winning phase. One output float4 (4 consecutive w') per
// thread; input cols 8t+j .. 8t+6+j covered by two contiguous float4 loads
// -> fully coalesced reads and writes.
__global__ void aps_gather(const float4* __restrict__ in,
                           const int* __restrict__ idxArr,
                           float4* __restrict__ out) {
    int o = blockIdx.x * blockDim.x + threadIdx.x;   // output float4 index
    int t  = o & 31;          // float4 index within output row
    int hp = (o >> 5) & 127;  // output row h'
    int bc = o >> 12;         // b*C + c
    int b  = bc / C;
    int phase = idxArr[b];    // wave-uniform (same b across a wave)
    int i = phase >> 1, j = phase & 1;
    const float4* row = in + ((size_t)bc * H + (2 * hp + i)) * F4_PER_ROW;
    float4 a  = row[2 * t];
    float4 c4 = row[2 * t + 1];
    float4 r;
    r.x = j ? a.y  : a.x;
    r.y = j ? a.w  : a.z;
    r.z = j ? c4.y : c4.x;
    r.w = j ? c4.w : c4.z;
    out[o] = r;
}

extern "C" void kernel_launch(void* const* d_in, const int* in_sizes, int n_in,
                              void* d_out, int out_size, void* d_ws, size_t ws_size,
                              hipStream_t stream) {
    const float4* in = (const float4*)d_in[0];
    float4* out = (float4*)d_out;
    float* partial = (float*)d_ws;                  // 32 KB of per-block partials
    int* idx = (int*)((char*)d_ws + 32768);         // 16 ints

    dim3 g1(GX, B);
    aps_norms<<<g1, BLK, 0, stream>>>(in, partial);
    aps_reduce_argmax<<<1, 1024, 0, stream>>>(partial, idx);
    aps_gather<<<OUT_F4 / 256, 256, 0, stream>>>(in, (const int*)idx, out);
}